// Round 5
// baseline (610.168 us; speedup 1.0000x reference)
//
#include <hip/hip_runtime.h>
#include <hip/hip_bf16.h>

#define DIM 2048
#define NHEADS 16
#define HEAD_DIM 128
#define HIDDEN 2048
#define SEQ 4096
#define BATCH 2
#define BT (BATCH * SEQ)        // 8192
#define NSEG 64
#define SEGLEN (SEQ / NSEG)     // 64
#define N_GATE (3 * HIDDEN)     // 6144

typedef __bf16 bf16_t;
typedef __bf16 bf16x8 __attribute__((ext_vector_type(8)));
typedef __bf16 bf16x4_t __attribute__((ext_vector_type(4)));
typedef float f32x4 __attribute__((ext_vector_type(4)));

__device__ __forceinline__ void gload_lds16(const void* g, void* l) {
  __builtin_amdgcn_global_load_lds(
      (const __attribute__((address_space(1))) void*)g,
      (__attribute__((address_space(3))) void*)l, 16, 0, 0);
}

#define MEMFENCE asm volatile("" ::: "memory")
#define BAR do { MEMFENCE; __builtin_amdgcn_s_barrier(); MEMFENCE; } while (0)
#define LGKM0 do { asm volatile("s_waitcnt lgkmcnt(0)" ::: "memory"); \
                   __builtin_amdgcn_sched_barrier(0); } while (0)
#define VMCNT(n) asm volatile("s_waitcnt vmcnt(" #n ")" ::: "memory")

// ---------------- prep: f32 -> bf16 convert (vectorized) ----------------
__global__ void cvt_f32_bf16(const float* __restrict__ src, bf16_t* __restrict__ dst, int n4) {
  int i = blockIdx.x * blockDim.x + threadIdx.x;
  if (i >= n4) return;
  float4 v = reinterpret_cast<const float4*>(src)[i];
  bf16x4_t o;
  o[0] = (bf16_t)v.x; o[1] = (bf16_t)v.y; o[2] = (bf16_t)v.z; o[3] = (bf16_t)v.w;
  reinterpret_cast<bf16x4_t*>(dst)[i] = o;
}

// ---------------- f gate in pure fp32 (precision-critical) ----------------
__global__ void fgate_kernel(const float* __restrict__ x, const float* __restrict__ Wg,
                             const float* __restrict__ bg, float* __restrict__ fout) {
  int idx = blockIdx.x * 256 + threadIdx.x;
  int bt = idx >> 4, h = idx & 15;
  const float* xr = x + (size_t)bt * DIM;
  const float* wr = Wg + (size_t)h * DIM;
  float acc = 0.f;
  for (int k = 0; k < DIM; k += 4) {
    float4 xv = *reinterpret_cast<const float4*>(xr + k);
    float4 wv = *reinterpret_cast<const float4*>(wr + k);
    acc = fmaf(xv.x, wv.x, acc);
    acc = fmaf(xv.y, wv.y, acc);
    acc = fmaf(xv.z, wv.z, acc);
    acc = fmaf(xv.w, wv.w, acc);
  }
  acc += bg[h];
  fout[idx] = 1.f / (1.f + expf(-acc));
}

// ---------------- 256x256 tile, BK=64, 2-slot dbuf, conflict-free-swizzle GEMM ----
// C = A * B^T, A (MxK) row-major, B (NxK) row-major, K = 2048 (KT = 32 tiles).
// LDS region = [slot][half][128 rows][64 cols] (128-B rows = exactly 32 banks).
// Chunk swizzle: 16B-chunk c (0..7) of row r stored at c ^ (r&7).
//   Read bank-group = (kh*4+q) ^ (rl&7): per quarter-wave 8 groups x 2 lanes
//   (2-way = free, m136); per wave 8 addrs/bank balanced. (r4's 64-B rows gave
//   only 4 groups/quarter-wave -> 4-way conflict -> MfmaUtil 22%.)
// Stage unit = block-wide 8KB (64 rows of one region); units/tile = 8.
// Per-tile issue order: B0j0,B0j1,B1j0,B1j1 (sp0,sp1), A0j0,A1j0 (sp2),
// A0j1,A1j1 (sp3) -> FIFO prefix-6 = exactly sp0's need-set.
// Waits: vmcnt(2) before sp0, vmcnt(2) before sp1 (vmcnt(0) at last tile);
// sp2/sp3 re-read the same regions (kh1 chunks) -> no wait, no barrier.
// Write-after-read: every staged region's last reader lgkm-drained >=2 barriers
// before the overwriting issue (verified per-region).

__device__ __forceinline__ void stage_unit(const bf16_t* __restrict__ G, int grow0, int kcol,
                                           bf16_t* region, int j, int wid, int lane) {
  const int r = j * 64 + wid * 8 + (lane >> 3);   // LDS row in region (0..127)
  const int c = (lane & 7) ^ (lane >> 3);          // data chunk for stored slot (lane&7)
  gload_lds16(G + (size_t)(grow0 + r) * 2048 + kcol + c * 8,
              region + (size_t)(j * 64 + wid * 8) * 64);  // + lane*16B (linear HW)
}

#define FRAG8(ptr, row, fo) (*reinterpret_cast<const bf16x8*>(&(ptr)[(size_t)(row) * 64 + (fo)]))

template <int MODE>
__global__ __launch_bounds__(512, 1)
void gemm256(const bf16_t* __restrict__ A, const bf16_t* __restrict__ B,
             const float* __restrict__ bias,
             bf16_t* __restrict__ Oi, bf16_t* __restrict__ Ot, bf16_t* __restrict__ Oo,
             float* __restrict__ Of, int tiles_n) {
  __shared__ __align__(16) bf16_t As[2][2][128 * 64];
  __shared__ __align__(16) bf16_t Bs[2][2][128 * 64];
  constexpr int KT = 32;  // 2048 / 64

  const int tid = threadIdx.x;
  const int wid = tid >> 6, lane = tid & 63;
  const int nwg = gridDim.x, bid = blockIdx.x;
  const int swz = (bid & 7) * (nwg >> 3) + (bid >> 3);      // bijective (nwg%8==0)
  const int tm = swz / tiles_n, tn = swz - tm * tiles_n;
  const int brow = tm * 256, bcol = tn * 256;
  const int wm = wid >> 2, wn = wid & 3;                     // 2M x 4N; wave out 128x64
  const int rl = lane & 15, q = lane >> 4;
  const int cx = rl & 7;
  const int fo0 = ((q ^ cx) << 3);                           // kh0 swizzled chunk offset
  const int fo1 = fo0 ^ 32;                                  // kh1 = chunk|4 -> ^32 elems
  const int bnh = wn >> 1, brl = (wn & 1) * 64;

  f32x4 acc[8][4] = {};

  // prologue: tile0 units in steady-state FIFO order
  stage_unit(B, bcol,       0, &Bs[0][0][0], 0, wid, lane);
  stage_unit(B, bcol,       0, &Bs[0][0][0], 1, wid, lane);
  stage_unit(B, bcol + 128, 0, &Bs[0][1][0], 0, wid, lane);
  stage_unit(B, bcol + 128, 0, &Bs[0][1][0], 1, wid, lane);
  stage_unit(A, brow,       0, &As[0][0][0], 0, wid, lane);
  stage_unit(A, brow + 128, 0, &As[0][1][0], 0, wid, lane);
  stage_unit(A, brow,       0, &As[0][0][0], 1, wid, lane);
  stage_unit(A, brow + 128, 0, &As[0][1][0], 1, wid, lane);

  for (int t = 0; t < KT; ++t) {
    const int s = t & 1, ns = s ^ 1;
    const bool s1 = (t + 1) < KT;
    const int kc1 = (t + 1) * 64;
    const bf16_t* a = &As[s][wm][0];
    const bf16_t* b = &Bs[s][bnh][0];
    bf16x8 af[4], bf[4];

    // ---- sp0: kh0 x mi-half0 ----
    VMCNT(2);   // confirm B(t) x4 + A(t)j0 x2 (leaves A(t)j1 in flight)
    BAR;
    if (s1) { stage_unit(B, bcol,       kc1, &Bs[ns][0][0], 0, wid, lane);
              stage_unit(B, bcol,       kc1, &Bs[ns][0][0], 1, wid, lane); }
#pragma unroll
    for (int ni = 0; ni < 4; ++ni) bf[ni] = FRAG8(b, brl + ni * 16 + rl, fo0);
#pragma unroll
    for (int m = 0; m < 4; ++m)    af[m]  = FRAG8(a, m * 16 + rl, fo0);
    LGKM0;
    __builtin_amdgcn_s_setprio(1);
#pragma unroll
    for (int m = 0; m < 4; ++m)
#pragma unroll
      for (int ni = 0; ni < 4; ++ni)
        acc[m][ni] = __builtin_amdgcn_mfma_f32_16x16x32_bf16(af[m], bf[ni], acc[m][ni], 0, 0, 0);
    __builtin_amdgcn_s_setprio(0);

    // ---- sp1: kh0 x mi-half1 ----
    if (s1) { VMCNT(2); } else { VMCNT(0); }   // confirm A(t)j1
    BAR;
    if (s1) { stage_unit(B, bcol + 128, kc1, &Bs[ns][1][0], 0, wid, lane);
              stage_unit(B, bcol + 128, kc1, &Bs[ns][1][0], 1, wid, lane); }
#pragma unroll
    for (int m = 0; m < 4; ++m) af[m] = FRAG8(a, 64 + m * 16 + rl, fo0);
    LGKM0;
    __builtin_amdgcn_s_setprio(1);
#pragma unroll
    for (int m = 0; m < 4; ++m)
#pragma unroll
      for (int ni = 0; ni < 4; ++ni)
        acc[4 + m][ni] = __builtin_amdgcn_mfma_f32_16x16x32_bf16(af[m], bf[ni], acc[4 + m][ni], 0, 0, 0);
    __builtin_amdgcn_s_setprio(0);

    // ---- sp2: kh1 x mi-half0 (same regions, kh1 chunks: no wait/barrier) ----
    if (s1) { stage_unit(A, brow,       kc1, &As[ns][0][0], 0, wid, lane);
              stage_unit(A, brow + 128, kc1, &As[ns][1][0], 0, wid, lane); }
#pragma unroll
    for (int ni = 0; ni < 4; ++ni) bf[ni] = FRAG8(b, brl + ni * 16 + rl, fo1);
#pragma unroll
    for (int m = 0; m < 4; ++m)    af[m]  = FRAG8(a, m * 16 + rl, fo1);
    LGKM0;
    __builtin_amdgcn_s_setprio(1);
#pragma unroll
    for (int m = 0; m < 4; ++m)
#pragma unroll
      for (int ni = 0; ni < 4; ++ni)
        acc[m][ni] = __builtin_amdgcn_mfma_f32_16x16x32_bf16(af[m], bf[ni], acc[m][ni], 0, 0, 0);
    __builtin_amdgcn_s_setprio(0);

    // ---- sp3: kh1 x mi-half1 ----
    if (s1) { stage_unit(A, brow,       kc1, &As[ns][0][0], 1, wid, lane);
              stage_unit(A, brow + 128, kc1, &As[ns][1][0], 1, wid, lane); }
#pragma unroll
    for (int m = 0; m < 4; ++m) af[m] = FRAG8(a, 64 + m * 16 + rl, fo1);
    LGKM0;
    __builtin_amdgcn_s_setprio(1);
#pragma unroll
    for (int m = 0; m < 4; ++m)
#pragma unroll
      for (int ni = 0; ni < 4; ++ni)
        acc[4 + m][ni] = __builtin_amdgcn_mfma_f32_16x16x32_bf16(af[m], bf[ni], acc[4 + m][ni], 0, 0, 0);
    __builtin_amdgcn_s_setprio(0);
  }

  // epilogue. C/D layout: col = lane&15, row = (lane>>4)*4 + q  [m89/m91]
  const int crow0 = brow + wm * 128;
  const int ccol0 = bcol + wn * 64;
  if (MODE == 0) {
    const int section = bcol >> 11;  // 256-tile lies fully inside one 2048-section
    bf16_t* dst = (section == 0) ? Oi : ((section == 1) ? Ot : Oo);
#pragma unroll
    for (int mi = 0; mi < 8; ++mi)
#pragma unroll
      for (int ni = 0; ni < 4; ++ni) {
        int gcol = ccol0 + ni * 16 + (lane & 15);
        int col = gcol & 2047;
        float bv = bias[gcol];
#pragma unroll
        for (int qq = 0; qq < 4; ++qq) {
          int row = crow0 + mi * 16 + (lane >> 4) * 4 + qq;
          float v = acc[mi][ni][qq] + bv;
          float aout;
          if (section == 0)      aout = 1.f / (1.f + __expf(-v));
          else if (section == 1) aout = tanhf(v);
          else                   aout = v;
          dst[(size_t)row * HIDDEN + col] = (bf16_t)aout;
        }
      }
  } else {
#pragma unroll
    for (int mi = 0; mi < 8; ++mi)
#pragma unroll
      for (int ni = 0; ni < 4; ++ni) {
        int col = ccol0 + ni * 16 + (lane & 15);
        float bv = bias[col];
#pragma unroll
        for (int qq = 0; qq < 4; ++qq) {
          int row = crow0 + mi * 16 + (lane >> 4) * 4 + qq;
          Of[(size_t)row * DIM + col] = acc[mi][ni][qq] + bv;
        }
      }
  }
}

// ---------------- segmented scan ----------------
__global__ void scan_pass1(const float* __restrict__ fg, const bf16_t* __restrict__ gi,
                           const bf16_t* __restrict__ gt, float* __restrict__ cend,
                           float* __restrict__ pseg) {
  int bx = blockIdx.x;
  int chblk = bx & 7, seg = (bx >> 3) & 63, b = bx >> 9;
  int ch = chblk * 256 + threadIdx.x;
  int head = ch >> 7;
  float c = 0.f, P = 1.f;
  size_t t0 = (size_t)b * SEQ + (size_t)seg * SEGLEN;
  for (int tt = 0; tt < SEGLEN; ++tt) {
    size_t bt = t0 + tt;
    float f = fg[bt * NHEADS + head];
    float iv = (float)gi[bt * HIDDEN + ch];
    float tv = (float)gt[bt * HIDDEN + ch];
    c = fmaf(f, c, iv * tv);
    P *= f;
  }
  size_t o = ((size_t)b * NSEG + seg) * HIDDEN + ch;
  cend[o] = c;
  pseg[o] = P;
}

__global__ void scan_pass2(const float* __restrict__ cend, const float* __restrict__ pseg,
                           float* __restrict__ cin) {
  int idx = blockIdx.x * 256 + threadIdx.x;  // 4096
  int b = idx >> 11, ch = idx & 2047;
  float C = 0.f;
  for (int s = 0; s < NSEG; ++s) {
    size_t o = ((size_t)b * NSEG + s) * HIDDEN + ch;
    cin[o] = C;
    C = cend[o] + pseg[o] * C;
  }
}

__global__ void scan_pass3(const float* __restrict__ fg, const bf16_t* __restrict__ gi,
                           const bf16_t* __restrict__ gt, const bf16_t* __restrict__ go,
                           const float* __restrict__ cin, bf16_t* __restrict__ h) {
  int bx = blockIdx.x;
  int chblk = bx & 7, seg = (bx >> 3) & 63, b = bx >> 9;
  int ch = chblk * 256 + threadIdx.x;
  int head = ch >> 7;
  float c = cin[((size_t)b * NSEG + seg) * HIDDEN + ch];
  size_t t0 = (size_t)b * SEQ + (size_t)seg * SEGLEN;
  for (int tt = 0; tt < SEGLEN; ++tt) {
    size_t bt = t0 + tt;
    float f = fg[bt * NHEADS + head];
    float iv = (float)gi[bt * HIDDEN + ch];
    float tv = (float)gt[bt * HIDDEN + ch];
    c = fmaf(f, c, iv * tv);
    float hv = (float)go[bt * HIDDEN + ch] * tanhf(c);
    h[bt * HIDDEN + ch] = (bf16_t)hv;
  }
}

extern "C" void kernel_launch(void* const* d_in, const int* in_sizes, int n_in,
                              void* d_out, int out_size, void* d_ws, size_t ws_size,
                              hipStream_t stream) {
  const float* x  = (const float*)d_in[0];
  const float* Wg = (const float*)d_in[1];
  const float* bg = (const float*)d_in[2];
  const float* Wo = (const float*)d_in[3];
  const float* bo = (const float*)d_in[4];
  float* out = (float*)d_out;

  char* ws = (char*)d_ws;
  size_t off = 0;
  auto alloc = [&](size_t bytes) -> void* {
    void* p = ws + off;
    off += (bytes + 255) & ~(size_t)255;
    return p;
  };
  bf16_t* xb   = (bf16_t*)alloc((size_t)BT * DIM * 2);
  bf16_t* wgb  = (bf16_t*)alloc((size_t)N_GATE * DIM * 2);
  bf16_t* wob  = (bf16_t*)alloc((size_t)DIM * HIDDEN * 2);
  float*  fg   = (float*)alloc((size_t)BT * NHEADS * 4);
  bf16_t* gi   = (bf16_t*)alloc((size_t)BT * HIDDEN * 2);
  bf16_t* gt   = (bf16_t*)alloc((size_t)BT * HIDDEN * 2);
  bf16_t* go   = (bf16_t*)alloc((size_t)BT * HIDDEN * 2);
  bf16_t* hbuf = (bf16_t*)alloc((size_t)BT * HIDDEN * 2);
  float*  cend = (float*)alloc((size_t)BATCH * NSEG * HIDDEN * 4);
  float*  pseg = (float*)alloc((size_t)BATCH * NSEG * HIDDEN * 4);
  float*  cin  = (float*)alloc((size_t)BATCH * NSEG * HIDDEN * 4);
  (void)ws_size; (void)in_sizes; (void)n_in; (void)out_size;

  // prep converts
  {
    int n4 = BT * DIM / 4;
    cvt_f32_bf16<<<(n4 + 255) / 256, 256, 0, stream>>>(x, xb, n4);
  }
  {
    int n4 = N_GATE * DIM / 4;
    cvt_f32_bf16<<<(n4 + 255) / 256, 256, 0, stream>>>(Wg + (size_t)NHEADS * DIM, wgb, n4);
  }
  {
    int n4 = DIM * HIDDEN / 4;
    cvt_f32_bf16<<<(n4 + 255) / 256, 256, 0, stream>>>(Wo, wob, n4);
  }

  // f gate in fp32
  fgate_kernel<<<(BT * NHEADS) / 256, 256, 0, stream>>>(x, Wg, bg, fg);

  // gates GEMM: M=8192, N=6144, K=2048 -> 32x24 = 768 tiles
  gemm256<0><<<768, 512, 0, stream>>>(xb, wgb, bg + NHEADS, gi, gt, go, nullptr, 24);

  // segmented scan
  scan_pass1<<<BATCH * NSEG * (HIDDEN / 256), 256, 0, stream>>>(fg, gi, gt, cend, pseg);
  scan_pass2<<<BATCH * HIDDEN / 256, 256, 0, stream>>>(cend, pseg, cin);
  scan_pass3<<<BATCH * NSEG * (HIDDEN / 256), 256, 0, stream>>>(fg, gi, gt, go, cin, hbuf);

  // output GEMM: M=8192, N=2048, K=2048 -> 32x8 = 256 tiles
  gemm256<1><<<256, 512, 0, stream>>>(hbuf, wob, bo, nullptr, nullptr, nullptr, out, 8);
}

// Round 7
// 511.095 us; speedup vs baseline: 1.1938x; 1.1938x over previous
//
#include <hip/hip_runtime.h>
#include <hip/hip_bf16.h>

#define DIM 2048
#define NHEADS 16
#define HEAD_DIM 128
#define HIDDEN 2048
#define SEQ 4096
#define BATCH 2
#define BT (BATCH * SEQ)        // 8192
#define NSEG 64
#define SEGLEN (SEQ / NSEG)     // 64
#define N_GATE (3 * HIDDEN)     // 6144

typedef __bf16 bf16_t;
typedef __bf16 bf16x8 __attribute__((ext_vector_type(8)));
typedef __bf16 bf16x4_t __attribute__((ext_vector_type(4)));
typedef float f32x4 __attribute__((ext_vector_type(4)));

__device__ __forceinline__ void gload_lds16(const void* g, void* l) {
  __builtin_amdgcn_global_load_lds(
      (const __attribute__((address_space(1))) void*)g,
      (__attribute__((address_space(3))) void*)l, 16, 0, 0);
}

#define MEMFENCE asm volatile("" ::: "memory")
#define BAR do { MEMFENCE; __builtin_amdgcn_s_barrier(); MEMFENCE; } while (0)
#define LGKM0 do { asm volatile("s_waitcnt lgkmcnt(0)" ::: "memory"); \
                   __builtin_amdgcn_sched_barrier(0); } while (0)
#define VMCNT(n) asm volatile("s_waitcnt vmcnt(" #n ")" ::: "memory")

// ---------------- prep: f32 -> bf16 convert (vectorized) ----------------
__global__ void cvt_f32_bf16(const float* __restrict__ src, bf16_t* __restrict__ dst, int n4) {
  int i = blockIdx.x * blockDim.x + threadIdx.x;
  if (i >= n4) return;
  float4 v = reinterpret_cast<const float4*>(src)[i];
  bf16x4_t o;
  o[0] = (bf16_t)v.x; o[1] = (bf16_t)v.y; o[2] = (bf16_t)v.z; o[3] = (bf16_t)v.w;
  reinterpret_cast<bf16x4_t*>(dst)[i] = o;
}

// ---------------- f gate in pure fp32 (precision-critical) ----------------
__global__ void fgate_kernel(const float* __restrict__ x, const float* __restrict__ Wg,
                             const float* __restrict__ bg, float* __restrict__ fout) {
  int idx = blockIdx.x * 256 + threadIdx.x;
  int bt = idx >> 4, h = idx & 15;
  const float* xr = x + (size_t)bt * DIM;
  const float* wr = Wg + (size_t)h * DIM;
  float acc = 0.f;
  for (int k = 0; k < DIM; k += 4) {
    float4 xv = *reinterpret_cast<const float4*>(xr + k);
    float4 wv = *reinterpret_cast<const float4*>(wr + k);
    acc = fmaf(xv.x, wv.x, acc);
    acc = fmaf(xv.y, wv.y, acc);
    acc = fmaf(xv.z, wv.z, acc);
    acc = fmaf(xv.w, wv.w, acc);
  }
  acc += bg[h];
  fout[idx] = 1.f / (1.f + expf(-acc));
}

// ------------- 256x256, BK=64, 2-slot dbuf, 4-phase barrier-sandwich GEMM -------------
// C = A * B^T, both row-major with K contiguous; K = 2048 (KT = 32 K-tiles).
// LDS (per slot): A = [quarter q][64 rows][64 cols], B = [256 rows][64 cols]; 128-B rows.
// Swizzle (verified 0-conflict in r5 PMC): 16B-chunk c of row r stored at c ^ (r&7);
// global_load_lds writes linearly so the source address is pre-swizzled (rule 21).
// Phase p (=M-quarter p): [ds_read frags; stage 2 units; (vmcnt)] BAR; lgkm0;
//   setprio(1); 16 MFMA; setprio(0); BAR.   (m201 8-phase skeleton, T3+T4+T5)
// Stage stream per tile t: p0: B(t+1)u0,u1 | p1: B(t+1)u2,u3 | p2: A(t+2)q0,q1 |
//   p3: A(t+2)q2, A(t+1)q3.  A-unit q dies at end of phase q -> sub-slot overwrite
//   race-free; B read only at p0.
// PROLOGUE (r6 NaN fix): must stage B(0)x4, A(0)x4 AND A(1)q0,q1,q2 (the steady
//   stream only provides A(t+1)q0..q2 from tile t-1; t=0 has no t-1). VMCNT(3).
// Ledger (per-thread FIFO): entering tile t outstanding = [A(t+1)q0,q1,q2, A(t)q3];
//   VMCNT(4)@p1 drains exactly those (A(t)q3 read at p3, 2-phase margin);
//   VMCNT(4)@p3 drains B(t+1)x4 (read t+1,p0). Tail: (KT-2,p3)=1, (KT-1,p1)=0.

__device__ __forceinline__ void stageA(const bf16_t* __restrict__ G, int brow, int kc,
                                       bf16_t* Aslot, int q, int wid, int lane) {
  const int rr = q * 64 + wid * 8;  // region-row base (wave-uniform)
  const int grow = brow + (wid >> 2) * 128 + q * 32 + (wid & 3) * 8 + (lane >> 3);
  const int gcol = kc + (((lane & 7) ^ (lane >> 3)) << 3);
  gload_lds16(G + (size_t)grow * 2048 + gcol, Aslot + (size_t)rr * 64);
}

__device__ __forceinline__ void stageB(const bf16_t* __restrict__ G, int bcol, int kc,
                                       bf16_t* Bslot, int j, int wid, int lane) {
  const int rr = (j >> 1) * 128 + (j & 1) * 64 + wid * 8;
  const int grow = bcol + rr + (lane >> 3);
  const int gcol = kc + (((lane & 7) ^ (lane >> 3)) << 3);
  gload_lds16(G + (size_t)grow * 2048 + gcol, Bslot + (size_t)rr * 64);
}

#define FRAG8(ptr, row, fo) (*reinterpret_cast<const bf16x8*>(&(ptr)[(size_t)(row) * 64 + (fo)]))

template <int MODE>
__global__ __launch_bounds__(512, 1)
void gemm256(const bf16_t* __restrict__ A, const bf16_t* __restrict__ B,
             const float* __restrict__ bias,
             bf16_t* __restrict__ Oi, bf16_t* __restrict__ Ot, bf16_t* __restrict__ Oo,
             float* __restrict__ Of, int tiles_n) {
  __shared__ __align__(16) bf16_t As[2][256 * 64];
  __shared__ __align__(16) bf16_t Bs[2][256 * 64];
  constexpr int KT = 32;  // 2048 / 64

  const int tid = threadIdx.x;
  const int wid = tid >> 6, lane = tid & 63;
  const int nwg = gridDim.x, bid = blockIdx.x;
  const int swz = (bid & 7) * (nwg >> 3) + (bid >> 3);      // bijective (nwg%8==0)
  const int tm = swz / tiles_n, tn = swz - tm * tiles_n;
  const int brow = tm * 256, bcol = tn * 256;
  const int wm = wid >> 2, wn = wid & 3;                     // 2M x 4N; wave out 128x64
  const int rl = lane & 15, qw = lane >> 4;
  const int fo0 = ((qw ^ (rl & 7)) << 3);                    // kh0 swizzled chunk offset
  const int fo1 = fo0 ^ 32;                                  // kh1 chunk = +4 -> ^32 elems
  const int brr = (wn >> 1) * 128 + (wn & 1) * 64;           // B region-row base (= wn*64)

  f32x4 acc[8][4] = {};

  // prologue: B(0)x4, A(0)x4, A(1)q0..q2 (r6 fix); drain all but the A(1) units
#pragma unroll
  for (int j = 0; j < 4; ++j) stageB(B, bcol, 0, &Bs[0][0], j, wid, lane);
#pragma unroll
  for (int qq = 0; qq < 4; ++qq) stageA(A, brow, 0, &As[0][0], qq, wid, lane);
#pragma unroll
  for (int qq = 0; qq < 3; ++qq) stageA(A, brow, 64, &As[1][0], qq, wid, lane);
  VMCNT(3);
  BAR;

  for (int t = 0; t < KT; ++t) {
    const int s = t & 1, ns = s ^ 1;
    const int kc1 = (t + 1) * 64, kc2 = (t + 2) * 64;
    const bool st1 = (t + 1) < KT, st2 = (t + 2) < KT;
    const bf16_t* Ar = &As[s][0];
    const bf16_t* Br = &Bs[s][0];
    bf16x8 bfr[2][4], af[2][2];

#define MFMA16(p)                                                                         \
  __builtin_amdgcn_s_setprio(1);                                                          \
  _Pragma("unroll")                                                                       \
  for (int mi = 0; mi < 2; ++mi)                                                          \
    _Pragma("unroll")                                                                     \
    for (int ni = 0; ni < 4; ++ni)                                                        \
      acc[(p)*2 + mi][ni] =                                                               \
          __builtin_amdgcn_mfma_f32_16x16x32_bf16(af[0][mi], bfr[0][ni], acc[(p)*2 + mi][ni], 0, 0, 0); \
  _Pragma("unroll")                                                                       \
  for (int mi = 0; mi < 2; ++mi)                                                          \
    _Pragma("unroll")                                                                     \
    for (int ni = 0; ni < 4; ++ni)                                                        \
      acc[(p)*2 + mi][ni] =                                                               \
          __builtin_amdgcn_mfma_f32_16x16x32_bf16(af[1][mi], bfr[1][ni], acc[(p)*2 + mi][ni], 0, 0, 0); \
  __builtin_amdgcn_s_setprio(0)

    // ---------- phase 0 (M-quarter 0; read all B frags) ----------
#pragma unroll
    for (int ni = 0; ni < 4; ++ni) {
      bfr[0][ni] = FRAG8(Br, brr + ni * 16 + rl, fo0);
      bfr[1][ni] = FRAG8(Br, brr + ni * 16 + rl, fo1);
    }
#pragma unroll
    for (int mi = 0; mi < 2; ++mi) {
      af[0][mi] = FRAG8(Ar, 0 * 64 + wm * 32 + mi * 16 + rl, fo0);
      af[1][mi] = FRAG8(Ar, 0 * 64 + wm * 32 + mi * 16 + rl, fo1);
    }
    if (st1) { stageB(B, bcol, kc1, &Bs[ns][0], 0, wid, lane);
               stageB(B, bcol, kc1, &Bs[ns][0], 1, wid, lane); }
    asm volatile("s_waitcnt lgkmcnt(8)" ::: "memory");
    BAR; LGKM0;
    MFMA16(0);
    BAR;

    // ---------- phase 1 (M-quarter 1) ----------
#pragma unroll
    for (int mi = 0; mi < 2; ++mi) {
      af[0][mi] = FRAG8(Ar, 1 * 64 + wm * 32 + mi * 16 + rl, fo0);
      af[1][mi] = FRAG8(Ar, 1 * 64 + wm * 32 + mi * 16 + rl, fo1);
    }
    if (st1) { stageB(B, bcol, kc1, &Bs[ns][0], 2, wid, lane);
               stageB(B, bcol, kc1, &Bs[ns][0], 3, wid, lane); }
    if (t < KT - 1) { VMCNT(4); } else { VMCNT(0); }   // drain A(t+1)q0..q2 + A(t)q3
    BAR; LGKM0;
    MFMA16(1);
    BAR;

    // ---------- phase 2 (M-quarter 2) ----------
#pragma unroll
    for (int mi = 0; mi < 2; ++mi) {
      af[0][mi] = FRAG8(Ar, 2 * 64 + wm * 32 + mi * 16 + rl, fo0);
      af[1][mi] = FRAG8(Ar, 2 * 64 + wm * 32 + mi * 16 + rl, fo1);
    }
    if (st2) { stageA(A, brow, kc2, &As[s][0], 0, wid, lane);   // q0 died at p0
               stageA(A, brow, kc2, &As[s][0], 1, wid, lane); } // q1 died at p1
    BAR; LGKM0;
    MFMA16(2);
    BAR;

    // ---------- phase 3 (M-quarter 3) ----------
#pragma unroll
    for (int mi = 0; mi < 2; ++mi) {
      af[0][mi] = FRAG8(Ar, 3 * 64 + wm * 32 + mi * 16 + rl, fo0);
      af[1][mi] = FRAG8(Ar, 3 * 64 + wm * 32 + mi * 16 + rl, fo1);
    }
    if (st2) stageA(A, brow, kc2, &As[s][0], 2, wid, lane);     // q2 died at p2
    if (st1) stageA(A, brow, kc1, &As[ns][0], 3, wid, lane);    // idle slot q3
    if (t < KT - 2) { VMCNT(4); }                               // drain B(t+1)x4
    else if (t == KT - 2) { VMCNT(1); }
    BAR; LGKM0;
    MFMA16(3);
    BAR;
#undef MFMA16
  }

  // epilogue. C/D layout: col = lane&15, row = (lane>>4)*4 + q  [m89/m91]
  const int crow0 = brow + wm * 128;
  const int ccol0 = bcol + wn * 64;
  if (MODE == 0) {
    const int section = bcol >> 11;  // 256-tile lies fully inside one 2048-section
    bf16_t* dst = (section == 0) ? Oi : ((section == 1) ? Ot : Oo);
#pragma unroll
    for (int mi = 0; mi < 8; ++mi)
#pragma unroll
      for (int ni = 0; ni < 4; ++ni) {
        int gcol = ccol0 + ni * 16 + (lane & 15);
        int col = gcol & 2047;
        float bv = bias[gcol];
#pragma unroll
        for (int qq = 0; qq < 4; ++qq) {
          int row = crow0 + mi * 16 + (lane >> 4) * 4 + qq;
          float v = acc[mi][ni][qq] + bv;
          float aout;
          if (section == 0)      aout = 1.f / (1.f + __expf(-v));
          else if (section == 1) aout = tanhf(v);
          else                   aout = v;
          dst[(size_t)row * HIDDEN + col] = (bf16_t)aout;
        }
      }
  } else {
#pragma unroll
    for (int mi = 0; mi < 8; ++mi)
#pragma unroll
      for (int ni = 0; ni < 4; ++ni) {
        int col = ccol0 + ni * 16 + (lane & 15);
        float bv = bias[col];
#pragma unroll
        for (int qq = 0; qq < 4; ++qq) {
          int row = crow0 + mi * 16 + (lane >> 4) * 4 + qq;
          Of[(size_t)row * DIM + col] = acc[mi][ni][qq] + bv;
        }
      }
  }
}

// ---------------- segmented scan ----------------
__global__ void scan_pass1(const float* __restrict__ fg, const bf16_t* __restrict__ gi,
                           const bf16_t* __restrict__ gt, float* __restrict__ cend,
                           float* __restrict__ pseg) {
  int bx = blockIdx.x;
  int chblk = bx & 7, seg = (bx >> 3) & 63, b = bx >> 9;
  int ch = chblk * 256 + threadIdx.x;
  int head = ch >> 7;
  float c = 0.f, P = 1.f;
  size_t t0 = (size_t)b * SEQ + (size_t)seg * SEGLEN;
  for (int tt = 0; tt < SEGLEN; ++tt) {
    size_t bt = t0 + tt;
    float f = fg[bt * NHEADS + head];
    float iv = (float)gi[bt * HIDDEN + ch];
    float tv = (float)gt[bt * HIDDEN + ch];
    c = fmaf(f, c, iv * tv);
    P *= f;
  }
  size_t o = ((size_t)b * NSEG + seg) * HIDDEN + ch;
  cend[o] = c;
  pseg[o] = P;
}

__global__ void scan_pass2(const float* __restrict__ cend, const float* __restrict__ pseg,
                           float* __restrict__ cin) {
  int idx = blockIdx.x * 256 + threadIdx.x;  // 4096
  int b = idx >> 11, ch = idx & 2047;
  float C = 0.f;
  for (int s = 0; s < NSEG; ++s) {
    size_t o = ((size_t)b * NSEG + s) * HIDDEN + ch;
    cin[o] = C;
    C = cend[o] + pseg[o] * C;
  }
}

__global__ void scan_pass3(const float* __restrict__ fg, const bf16_t* __restrict__ gi,
                           const bf16_t* __restrict__ gt, const bf16_t* __restrict__ go,
                           const float* __restrict__ cin, bf16_t* __restrict__ h) {
  int bx = blockIdx.x;
  int chblk = bx & 7, seg = (bx >> 3) & 63, b = bx >> 9;
  int ch = chblk * 256 + threadIdx.x;
  int head = ch >> 7;
  float c = cin[((size_t)b * NSEG + seg) * HIDDEN + ch];
  size_t t0 = (size_t)b * SEQ + (size_t)seg * SEGLEN;
  for (int tt = 0; tt < SEGLEN; ++tt) {
    size_t bt = t0 + tt;
    float f = fg[bt * NHEADS + head];
    float iv = (float)gi[bt * HIDDEN + ch];
    float tv = (float)gt[bt * HIDDEN + ch];
    c = fmaf(f, c, iv * tv);
    float hv = (float)go[bt * HIDDEN + ch] * tanhf(c);
    h[bt * HIDDEN + ch] = (bf16_t)hv;
  }
}

extern "C" void kernel_launch(void* const* d_in, const int* in_sizes, int n_in,
                              void* d_out, int out_size, void* d_ws, size_t ws_size,
                              hipStream_t stream) {
  const float* x  = (const float*)d_in[0];
  const float* Wg = (const float*)d_in[1];
  const float* bg = (const float*)d_in[2];
  const float* Wo = (const float*)d_in[3];
  const float* bo = (const float*)d_in[4];
  float* out = (float*)d_out;

  char* ws = (char*)d_ws;
  size_t off = 0;
  auto alloc = [&](size_t bytes) -> void* {
    void* p = ws + off;
    off += (bytes + 255) & ~(size_t)255;
    return p;
  };
  bf16_t* xb   = (bf16_t*)alloc((size_t)BT * DIM * 2);
  bf16_t* wgb  = (bf16_t*)alloc((size_t)N_GATE * DIM * 2);
  bf16_t* wob  = (bf16_t*)alloc((size_t)DIM * HIDDEN * 2);
  float*  fg   = (float*)alloc((size_t)BT * NHEADS * 4);
  bf16_t* gi   = (bf16_t*)alloc((size_t)BT * HIDDEN * 2);
  bf16_t* gt   = (bf16_t*)alloc((size_t)BT * HIDDEN * 2);
  bf16_t* go   = (bf16_t*)alloc((size_t)BT * HIDDEN * 2);
  bf16_t* hbuf = (bf16_t*)alloc((size_t)BT * HIDDEN * 2);
  float*  cend = (float*)alloc((size_t)BATCH * NSEG * HIDDEN * 4);
  float*  pseg = (float*)alloc((size_t)BATCH * NSEG * HIDDEN * 4);
  float*  cin  = (float*)alloc((size_t)BATCH * NSEG * HIDDEN * 4);
  (void)ws_size; (void)in_sizes; (void)n_in; (void)out_size;

  // prep converts
  {
    int n4 = BT * DIM / 4;
    cvt_f32_bf16<<<(n4 + 255) / 256, 256, 0, stream>>>(x, xb, n4);
  }
  {
    int n4 = N_GATE * DIM / 4;
    cvt_f32_bf16<<<(n4 + 255) / 256, 256, 0, stream>>>(Wg + (size_t)NHEADS * DIM, wgb, n4);
  }
  {
    int n4 = DIM * HIDDEN / 4;
    cvt_f32_bf16<<<(n4 + 255) / 256, 256, 0, stream>>>(Wo, wob, n4);
  }

  // f gate in fp32
  fgate_kernel<<<(BT * NHEADS) / 256, 256, 0, stream>>>(x, Wg, bg, fg);

  // gates GEMM: M=8192, N=6144, K=2048 -> 32x24 = 768 tiles
  gemm256<0><<<768, 512, 0, stream>>>(xb, wgb, bg + NHEADS, gi, gt, go, nullptr, 24);

  // segmented scan
  scan_pass1<<<BATCH * NSEG * (HIDDEN / 256), 256, 0, stream>>>(fg, gi, gt, cend, pseg);
  scan_pass2<<<BATCH * HIDDEN / 256, 256, 0, stream>>>(cend, pseg, cin);
  scan_pass3<<<BATCH * NSEG * (HIDDEN / 256), 256, 0, stream>>>(fg, gi, gt, go, cin, hbuf);

  // output GEMM: M=8192, N=2048, K=2048 -> 32x8 = 256 tiles
  gemm256<1><<<256, 512, 0, stream>>>(hbuf, wob, bo, nullptr, nullptr, nullptr, out, 8);
}

// Round 8
// 498.818 us; speedup vs baseline: 1.2232x; 1.0246x over previous
//
#include <hip/hip_runtime.h>
#include <hip/hip_bf16.h>

#define DIM 2048
#define NHEADS 16
#define HEAD_DIM 128
#define HIDDEN 2048
#define SEQ 4096
#define BATCH 2
#define BT (BATCH * SEQ)        // 8192
#define NSEG 64
#define SEGLEN (SEQ / NSEG)     // 64
#define N_GATE (3 * HIDDEN)     // 6144

typedef __bf16 bf16_t;
typedef __bf16 bf16x8 __attribute__((ext_vector_type(8)));
typedef __bf16 bf16x4_t __attribute__((ext_vector_type(4)));
typedef float f32x4 __attribute__((ext_vector_type(4)));

__device__ __forceinline__ void gload_lds16(const void* g, void* l) {
  __builtin_amdgcn_global_load_lds(
      (const __attribute__((address_space(1))) void*)g,
      (__attribute__((address_space(3))) void*)l, 16, 0, 0);
}

#define MEMFENCE asm volatile("" ::: "memory")
#define BAR do { MEMFENCE; __builtin_amdgcn_s_barrier(); MEMFENCE; } while (0)
#define VMCNT(n) asm volatile("s_waitcnt vmcnt(" #n ")" ::: "memory")

// ---------------- prep: f32 -> bf16 convert (vectorized) ----------------
__global__ void cvt_f32_bf16(const float* __restrict__ src, bf16_t* __restrict__ dst, int n4) {
  int i = blockIdx.x * blockDim.x + threadIdx.x;
  if (i >= n4) return;
  float4 v = reinterpret_cast<const float4*>(src)[i];
  bf16x4_t o;
  o[0] = (bf16_t)v.x; o[1] = (bf16_t)v.y; o[2] = (bf16_t)v.z; o[3] = (bf16_t)v.w;
  reinterpret_cast<bf16x4_t*>(dst)[i] = o;
}

// ---------------- f gate in pure fp32 (precision-critical) ----------------
__global__ void fgate_kernel(const float* __restrict__ x, const float* __restrict__ Wg,
                             const float* __restrict__ bg, float* __restrict__ fout) {
  int idx = blockIdx.x * 256 + threadIdx.x;
  int bt = idx >> 4, h = idx & 15;
  const float* xr = x + (size_t)bt * DIM;
  const float* wr = Wg + (size_t)h * DIM;
  float acc = 0.f;
  for (int k = 0; k < DIM; k += 4) {
    float4 xv = *reinterpret_cast<const float4*>(xr + k);
    float4 wv = *reinterpret_cast<const float4*>(wr + k);
    acc = fmaf(xv.x, wv.x, acc);
    acc = fmaf(xv.y, wv.y, acc);
    acc = fmaf(xv.z, wv.z, acc);
    acc = fmaf(xv.w, wv.w, acc);
  }
  acc += bg[h];
  fout[idx] = 1.f / (1.f + expf(-acc));
}

// ------------- 256x256, BK=64, 2-slot dbuf, 4-phase single-barrier GEMM -------------
// C = A * B^T, both row-major with K contiguous; K = 2048 (KT = 32 K-tiles).
// LDS (per slot): A = [quarter q][64 rows][64 cols], B = [256 rows][64 cols]; 128-B rows.
// Swizzle (0-conflict, r5/r7 PMC): 16B-chunk c of row r stored at c ^ (r&7); source
// pre-swizzled (rule 21), un-applied on ds_read.
// r8 change vs r7: ONE barrier per phase (before the MFMA cluster), no LGKM0,
// no sched_barrier — compiler free-schedules reads(p+1)/stages(p+1) into the
// MFMA16(p) region with its own fine-grained lgkmcnt (m97 evidence). vmcnt
// ledger UNCHANGED from r7 (placements @p1/@p3 + tail).
// Safety (one-barrier model; LDS reads execute at issue):
//   overwrite-issue >= 1 barrier after victim's last read-issue:
//   A(t)q0 read@p0-top -> staged@p2 (2 BARs); q1@p1 -> p2 (1 BAR); q2@p2 -> p3
//   (1 BAR); q3@p3 -> (t+1,p3) (4 BARs); B slot: 4 BARs. Staged-visibility:
//   every unit vmcnt-confirmed + >=1 BAR before first read (r7 ledger).

__device__ __forceinline__ void stageA(const bf16_t* __restrict__ G, int brow, int kc,
                                       bf16_t* Aslot, int q, int wid, int lane) {
  const int rr = q * 64 + wid * 8;  // region-row base (wave-uniform)
  const int grow = brow + (wid >> 2) * 128 + q * 32 + (wid & 3) * 8 + (lane >> 3);
  const int gcol = kc + (((lane & 7) ^ (lane >> 3)) << 3);
  gload_lds16(G + (size_t)grow * 2048 + gcol, Aslot + (size_t)rr * 64);
}

__device__ __forceinline__ void stageB(const bf16_t* __restrict__ G, int bcol, int kc,
                                       bf16_t* Bslot, int j, int wid, int lane) {
  const int rr = (j >> 1) * 128 + (j & 1) * 64 + wid * 8;
  const int grow = bcol + rr + (lane >> 3);
  const int gcol = kc + (((lane & 7) ^ (lane >> 3)) << 3);
  gload_lds16(G + (size_t)grow * 2048 + gcol, Bslot + (size_t)rr * 64);
}

#define FRAG8(ptr, row, fo) (*reinterpret_cast<const bf16x8*>(&(ptr)[(size_t)(row) * 64 + (fo)]))

template <int MODE>
__global__ __launch_bounds__(512, 1)
void gemm256(const bf16_t* __restrict__ A, const bf16_t* __restrict__ B,
             const float* __restrict__ bias,
             bf16_t* __restrict__ Oi, bf16_t* __restrict__ Ot, bf16_t* __restrict__ Oo,
             float* __restrict__ Of, int tiles_n) {
  __shared__ __align__(16) bf16_t As[2][256 * 64];
  __shared__ __align__(16) bf16_t Bs[2][256 * 64];
  constexpr int KT = 32;  // 2048 / 64

  const int tid = threadIdx.x;
  const int wid = tid >> 6, lane = tid & 63;
  const int nwg = gridDim.x, bid = blockIdx.x;
  const int swz = (bid & 7) * (nwg >> 3) + (bid >> 3);      // bijective (nwg%8==0)
  const int tm = swz / tiles_n, tn = swz - tm * tiles_n;
  const int brow = tm * 256, bcol = tn * 256;
  const int wm = wid >> 2, wn = wid & 3;                     // 2M x 4N; wave out 128x64
  const int rl = lane & 15, qw = lane >> 4;
  const int fo0 = ((qw ^ (rl & 7)) << 3);                    // kh0 swizzled chunk offset
  const int fo1 = fo0 ^ 32;                                  // kh1 chunk = +4 -> ^32 elems
  const int brr = (wn >> 1) * 128 + (wn & 1) * 64;           // B region-row base (= wn*64)

  f32x4 acc[8][4] = {};

  // prologue: B(0)x4, A(0)x4, A(1)q0..q2; drain all but the 3 A(1) units
#pragma unroll
  for (int j = 0; j < 4; ++j) stageB(B, bcol, 0, &Bs[0][0], j, wid, lane);
#pragma unroll
  for (int qq = 0; qq < 4; ++qq) stageA(A, brow, 0, &As[0][0], qq, wid, lane);
#pragma unroll
  for (int qq = 0; qq < 3; ++qq) stageA(A, brow, 64, &As[1][0], qq, wid, lane);
  VMCNT(3);
  BAR;

  for (int t = 0; t < KT; ++t) {
    const int s = t & 1, ns = s ^ 1;
    const int kc1 = (t + 1) * 64, kc2 = (t + 2) * 64;
    const bool st1 = (t + 1) < KT, st2 = (t + 2) < KT;
    const bf16_t* Ar = &As[s][0];
    const bf16_t* Br = &Bs[s][0];
    bf16x8 bfr[2][4], af[2][2];

#define MFMA16(p)                                                                         \
  __builtin_amdgcn_s_setprio(1);                                                          \
  _Pragma("unroll")                                                                       \
  for (int mi = 0; mi < 2; ++mi)                                                          \
    _Pragma("unroll")                                                                     \
    for (int ni = 0; ni < 4; ++ni)                                                        \
      acc[(p)*2 + mi][ni] =                                                               \
          __builtin_amdgcn_mfma_f32_16x16x32_bf16(af[0][mi], bfr[0][ni], acc[(p)*2 + mi][ni], 0, 0, 0); \
  _Pragma("unroll")                                                                       \
  for (int mi = 0; mi < 2; ++mi)                                                          \
    _Pragma("unroll")                                                                     \
    for (int ni = 0; ni < 4; ++ni)                                                        \
      acc[(p)*2 + mi][ni] =                                                               \
          __builtin_amdgcn_mfma_f32_16x16x32_bf16(af[1][mi], bfr[1][ni], acc[(p)*2 + mi][ni], 0, 0, 0); \
  __builtin_amdgcn_s_setprio(0)

    // ---------- phase 0 (M-quarter 0; read all B frags) ----------
#pragma unroll
    for (int ni = 0; ni < 4; ++ni) {
      bfr[0][ni] = FRAG8(Br, brr + ni * 16 + rl, fo0);
      bfr[1][ni] = FRAG8(Br, brr + ni * 16 + rl, fo1);
    }
#pragma unroll
    for (int mi = 0; mi < 2; ++mi) {
      af[0][mi] = FRAG8(Ar, 0 * 64 + wm * 32 + mi * 16 + rl, fo0);
      af[1][mi] = FRAG8(Ar, 0 * 64 + wm * 32 + mi * 16 + rl, fo1);
    }
    if (st1) { stageB(B, bcol, kc1, &Bs[ns][0], 0, wid, lane);
               stageB(B, bcol, kc1, &Bs[ns][0], 1, wid, lane); }
    BAR;
    MFMA16(0);

    // ---------- phase 1 (M-quarter 1) ----------
#pragma unroll
    for (int mi = 0; mi < 2; ++mi) {
      af[0][mi] = FRAG8(Ar, 1 * 64 + wm * 32 + mi * 16 + rl, fo0);
      af[1][mi] = FRAG8(Ar, 1 * 64 + wm * 32 + mi * 16 + rl, fo1);
    }
    if (st1) { stageB(B, bcol, kc1, &Bs[ns][0], 2, wid, lane);
               stageB(B, bcol, kc1, &Bs[ns][0], 3, wid, lane); }
    if (t < KT - 1) { VMCNT(4); } else { VMCNT(0); }   // drain A(t+1)q0..q2 + A(t)q3
    BAR;
    MFMA16(1);

    // ---------- phase 2 (M-quarter 2) ----------
#pragma unroll
    for (int mi = 0; mi < 2; ++mi) {
      af[0][mi] = FRAG8(Ar, 2 * 64 + wm * 32 + mi * 16 + rl, fo0);
      af[1][mi] = FRAG8(Ar, 2 * 64 + wm * 32 + mi * 16 + rl, fo1);
    }
    if (st2) { stageA(A, brow, kc2, &As[s][0], 0, wid, lane);   // q0 read@p0 (2 BARs back)
               stageA(A, brow, kc2, &As[s][0], 1, wid, lane); } // q1 read@p1 (1 BAR back)
    BAR;
    MFMA16(2);

    // ---------- phase 3 (M-quarter 3) ----------
#pragma unroll
    for (int mi = 0; mi < 2; ++mi) {
      af[0][mi] = FRAG8(Ar, 3 * 64 + wm * 32 + mi * 16 + rl, fo0);
      af[1][mi] = FRAG8(Ar, 3 * 64 + wm * 32 + mi * 16 + rl, fo1);
    }
    if (st2) stageA(A, brow, kc2, &As[s][0], 2, wid, lane);     // q2 read@p2 (1 BAR back)
    if (st1) stageA(A, brow, kc1, &As[ns][0], 3, wid, lane);    // idle-slot q3
    if (t < KT - 2) { VMCNT(4); }                               // drain B(t+1)x4
    else if (t == KT - 2) { VMCNT(1); }
    BAR;
    MFMA16(3);
#undef MFMA16
  }

  // epilogue. C/D layout: col = lane&15, row = (lane>>4)*4 + q  [m89/m91]
  const int crow0 = brow + wm * 128;
  const int ccol0 = bcol + wn * 64;
  if (MODE == 0) {
    const int section = bcol >> 11;  // 256-tile lies fully inside one 2048-section
    bf16_t* dst = (section == 0) ? Oi : ((section == 1) ? Ot : Oo);
#pragma unroll
    for (int mi = 0; mi < 8; ++mi)
#pragma unroll
      for (int ni = 0; ni < 4; ++ni) {
        int gcol = ccol0 + ni * 16 + (lane & 15);
        int col = gcol & 2047;
        float bv = bias[gcol];
#pragma unroll
        for (int qq = 0; qq < 4; ++qq) {
          int row = crow0 + mi * 16 + (lane >> 4) * 4 + qq;
          float v = acc[mi][ni][qq] + bv;
          float aout;
          if (section == 0)      aout = 1.f / (1.f + __expf(-v));
          else if (section == 1) aout = tanhf(v);
          else                   aout = v;
          dst[(size_t)row * HIDDEN + col] = (bf16_t)aout;
        }
      }
  } else {
#pragma unroll
    for (int mi = 0; mi < 8; ++mi)
#pragma unroll
      for (int ni = 0; ni < 4; ++ni) {
        int col = ccol0 + ni * 16 + (lane & 15);
        float bv = bias[col];
#pragma unroll
        for (int qq = 0; qq < 4; ++qq) {
          int row = crow0 + mi * 16 + (lane >> 4) * 4 + qq;
          Of[(size_t)row * DIM + col] = acc[mi][ni][qq] + bv;
        }
      }
  }
}

// ---------------- segmented scan ----------------
__global__ void scan_pass1(const float* __restrict__ fg, const bf16_t* __restrict__ gi,
                           const bf16_t* __restrict__ gt, float* __restrict__ cend,
                           float* __restrict__ pseg) {
  int bx = blockIdx.x;
  int chblk = bx & 7, seg = (bx >> 3) & 63, b = bx >> 9;
  int ch = chblk * 256 + threadIdx.x;
  int head = ch >> 7;
  float c = 0.f, P = 1.f;
  size_t t0 = (size_t)b * SEQ + (size_t)seg * SEGLEN;
  for (int tt = 0; tt < SEGLEN; ++tt) {
    size_t bt = t0 + tt;
    float f = fg[bt * NHEADS + head];
    float iv = (float)gi[bt * HIDDEN + ch];
    float tv = (float)gt[bt * HIDDEN + ch];
    c = fmaf(f, c, iv * tv);
    P *= f;
  }
  size_t o = ((size_t)b * NSEG + seg) * HIDDEN + ch;
  cend[o] = c;
  pseg[o] = P;
}

__global__ void scan_pass2(const float* __restrict__ cend, const float* __restrict__ pseg,
                           float* __restrict__ cin) {
  int idx = blockIdx.x * 256 + threadIdx.x;  // 4096
  int b = idx >> 11, ch = idx & 2047;
  float C = 0.f;
  for (int s = 0; s < NSEG; ++s) {
    size_t o = ((size_t)b * NSEG + s) * HIDDEN + ch;
    cin[o] = C;
    C = cend[o] + pseg[o] * C;
  }
}

__global__ void scan_pass3(const float* __restrict__ fg, const bf16_t* __restrict__ gi,
                           const bf16_t* __restrict__ gt, const bf16_t* __restrict__ go,
                           const float* __restrict__ cin, bf16_t* __restrict__ h) {
  int bx = blockIdx.x;
  int chblk = bx & 7, seg = (bx >> 3) & 63, b = bx >> 9;
  int ch = chblk * 256 + threadIdx.x;
  int head = ch >> 7;
  float c = cin[((size_t)b * NSEG + seg) * HIDDEN + ch];
  size_t t0 = (size_t)b * SEQ + (size_t)seg * SEGLEN;
  for (int tt = 0; tt < SEGLEN; ++tt) {
    size_t bt = t0 + tt;
    float f = fg[bt * NHEADS + head];
    float iv = (float)gi[bt * HIDDEN + ch];
    float tv = (float)gt[bt * HIDDEN + ch];
    c = fmaf(f, c, iv * tv);
    float hv = (float)go[bt * HIDDEN + ch] * tanhf(c);
    h[bt * HIDDEN + ch] = (bf16_t)hv;
  }
}

extern "C" void kernel_launch(void* const* d_in, const int* in_sizes, int n_in,
                              void* d_out, int out_size, void* d_ws, size_t ws_size,
                              hipStream_t stream) {
  const float* x  = (const float*)d_in[0];
  const float* Wg = (const float*)d_in[1];
  const float* bg = (const float*)d_in[2];
  const float* Wo = (const float*)d_in[3];
  const float* bo = (const float*)d_in[4];
  float* out = (float*)d_out;

  char* ws = (char*)d_ws;
  size_t off = 0;
  auto alloc = [&](size_t bytes) -> void* {
    void* p = ws + off;
    off += (bytes + 255) & ~(size_t)255;
    return p;
  };
  bf16_t* xb   = (bf16_t*)alloc((size_t)BT * DIM * 2);
  bf16_t* wgb  = (bf16_t*)alloc((size_t)N_GATE * DIM * 2);
  bf16_t* wob  = (bf16_t*)alloc((size_t)DIM * HIDDEN * 2);
  float*  fg   = (float*)alloc((size_t)BT * NHEADS * 4);
  bf16_t* gi   = (bf16_t*)alloc((size_t)BT * HIDDEN * 2);
  bf16_t* gt   = (bf16_t*)alloc((size_t)BT * HIDDEN * 2);
  bf16_t* go   = (bf16_t*)alloc((size_t)BT * HIDDEN * 2);
  bf16_t* hbuf = (bf16_t*)alloc((size_t)BT * HIDDEN * 2);
  float*  cend = (float*)alloc((size_t)BATCH * NSEG * HIDDEN * 4);
  float*  pseg = (float*)alloc((size_t)BATCH * NSEG * HIDDEN * 4);
  float*  cin  = (float*)alloc((size_t)BATCH * NSEG * HIDDEN * 4);
  (void)ws_size; (void)in_sizes; (void)n_in; (void)out_size;

  // prep converts
  {
    int n4 = BT * DIM / 4;
    cvt_f32_bf16<<<(n4 + 255) / 256, 256, 0, stream>>>(x, xb, n4);
  }
  {
    int n4 = N_GATE * DIM / 4;
    cvt_f32_bf16<<<(n4 + 255) / 256, 256, 0, stream>>>(Wg + (size_t)NHEADS * DIM, wgb, n4);
  }
  {
    int n4 = DIM * HIDDEN / 4;
    cvt_f32_bf16<<<(n4 + 255) / 256, 256, 0, stream>>>(Wo, wob, n4);
  }

  // f gate in fp32
  fgate_kernel<<<(BT * NHEADS) / 256, 256, 0, stream>>>(x, Wg, bg, fg);

  // gates GEMM: M=8192, N=6144, K=2048 -> 32x24 = 768 tiles
  gemm256<0><<<768, 512, 0, stream>>>(xb, wgb, bg + NHEADS, gi, gt, go, nullptr, 24);

  // segmented scan
  scan_pass1<<<BATCH * NSEG * (HIDDEN / 256), 256, 0, stream>>>(fg, gi, gt, cend, pseg);
  scan_pass2<<<BATCH * HIDDEN / 256, 256, 0, stream>>>(cend, pseg, cin);
  scan_pass3<<<BATCH * NSEG * (HIDDEN / 256), 256, 0, stream>>>(fg, gi, gt, go, cin, hbuf);

  // output GEMM: M=8192, N=2048, K=2048 -> 32x8 = 256 tiles
  gemm256<1><<<256, 512, 0, stream>>>(hbuf, wob, bo, nullptr, nullptr, nullptr, out, 8);
}